// Round 7
// baseline (269.558 us; speedup 1.0000x reference)
//
#include <hip/hip_runtime.h>

typedef __attribute__((ext_vector_type(8))) short short8;
typedef __attribute__((ext_vector_type(4))) float f32x4;
typedef unsigned short u16;
typedef unsigned int u32;

#define MFMA_BF16(a, b, c) __builtin_amdgcn_mfma_f32_16x16x32_bf16((a), (b), (c), 0, 0, 0)

constexpr int D = 1024;
constexpr int L = 2048;
constexpr int NHEAD = 16;
constexpr int HD = 64;
// fold softmax scale (1/8) and log2(e) into q at projection time
constexpr float QLAMBDA = 0.125f * 1.44269504088896340736f;

__device__ __forceinline__ u16 f2bf(float f) {
  unsigned u = __builtin_bit_cast(unsigned, f);
  u = (u + 0x7fffu + ((u >> 16) & 1u)) >> 16;
  return (u16)u;
}

__device__ __forceinline__ short8 cvt8(f32x4 lo, f32x4 hi) {
  short8 r;
  r[0] = (short)f2bf(lo[0]); r[1] = (short)f2bf(lo[1]);
  r[2] = (short)f2bf(lo[2]); r[3] = (short)f2bf(lo[3]);
  r[4] = (short)f2bf(hi[0]); r[5] = (short)f2bf(hi[1]);
  r[6] = (short)f2bf(hi[2]); r[7] = (short)f2bf(hi[3]);
  return r;
}

// async global->LDS, 16B per lane. dst must be wave-uniform; per-lane global src.
__device__ __forceinline__ void gload16(const u16* src, u16* dst) {
  __builtin_amdgcn_global_load_lds(
      (const __attribute__((address_space(1))) u32*)(src),
      (__attribute__((address_space(3))) u32*)(dst), 16, 0, 0);
}

// ---------- merged prep: weight transpose | RoPE tables | X f32->bf16 ----------
// blocks [0,4096): wT transpose+convert; [4096,4352): rope tables;
// [4352,10496): cvt of Q,K,V (only when DO_CVT).
template <bool DO_CVT>
__global__ __launch_bounds__(256) void prep_kernel(
    const float* W0, const float* W1, const float* W2, const float* W3, u16* wTout,
    float* ct, float* st,
    const float* Q, const float* K, const float* V, u16* xb) {
  int i = blockIdx.x;
  if (i < 4096) {
    int z = i >> 10, bx = i & 31, by = (i >> 5) & 31;
    const float* W = z == 0 ? W0 : z == 1 ? W1 : z == 2 ? W2 : W3;
    u16* o = wTout + (size_t)z * D * D;
    __shared__ float t[32][33];
    int x = threadIdx.x & 31, y = threadIdx.x >> 5;
    int k0 = bx * 32, n0 = by * 32;
#pragma unroll
    for (int q = 0; q < 4; q++) {
      int ky = y * 4 + q;
      t[ky][x] = W[(size_t)(k0 + ky) * D + n0 + x];
    }
    __syncthreads();
#pragma unroll
    for (int q = 0; q < 4; q++) {
      int ny = y * 4 + q;
      o[(size_t)(n0 + ny) * D + k0 + x] = f2bf(t[x][ny]);
    }
  } else if (i < 4352) {
    int t = (i - 4096) * 256 + threadIdx.x;  // L*32 = 65536
    int ii = t & 31, pos = t >> 5;
    float invf = powf(10000.0f, -(float)ii / 32.0f);
    float ang = (float)pos * invf;
    ct[t] = cosf(ang);
    st[t] = sinf(ang);
  } else if constexpr (DO_CVT) {
    int j = i - 4352;
    int zz = j / 2048, bx = j - zz * 2048;
    const float* src = zz == 0 ? Q : zz == 1 ? K : V;
    u16* dst = xb + (size_t)zz * 4096 * D;
    int t = bx * 256 + threadIdx.x;
    const float* p = src + (size_t)t * 8;
    f32x4 lo = *(const f32x4*)p;
    f32x4 hi = *(const f32x4*)(p + 4);
    *(short8*)(dst + (size_t)t * 8) = cvt8(lo, hi);
  }
}

// ======== staged GEMM core (128x128 tile, BK=32, LDS dbuf, gload_lds) ========

// ---------- fused QKV projection GEMM + bias + RoPE epilogue ----------
__global__ __launch_bounds__(256, 3) void proj_gemm_staged(
    const u16* xb, const u16* wT,
    const float* bq, const float* bk, const float* bv,
    const float* ct, const float* st,
    u16* qo, u16* ko, u16* vT) {
  int i = blockIdx.x;  // 768 blocks, bijective XCD swizzle (768%8==0)
  int swz = (i & 7) * 96 + (i >> 3);
  int z = swz >> 8;
  int bx = swz & 7;
  int by = (swz >> 3) & 31;

  const u16* A = xb + (size_t)z * 4096 * D;
  const u16* W = wT + (size_t)z * D * D;
  const float* bias = z == 0 ? bq : z == 1 ? bk : bv;

  int w = threadIdx.x >> 6, lane = threadIdx.x & 63;
  int r = lane & 15, c = lane >> 4;
  int wr = w >> 1, wc = w & 1;
  int m0 = by * 128 + wr * 64;
  int n0 = bx * 128 + wc * 64;

  __shared__ __align__(16) u16 lsA[2][4096];
  __shared__ __align__(16) u16 lsB[2][4096];

  const u16* aSrc[2];
  const u16* bSrc[2];
  int dstOff[2];
#pragma unroll
  for (int i2 = 0; i2 < 2; i2++) {
    int q0 = i2 * 256 + w * 64;
    int qq = q0 + lane;
    int t = qq >> 2;
    int gch = (qq & 3) ^ ((t >> 1) & 3);
    aSrc[i2] = A + (size_t)(by * 128 + t) * D + gch * 8;
    bSrc[i2] = W + (size_t)(bx * 128 + t) * D + gch * 8;
    dstOff[i2] = q0 * 8;
  }

  int aOff[4], bOff[4];
#pragma unroll
  for (int mi = 0; mi < 4; mi++) {
    int rowA = wr * 64 + mi * 16 + r;
    aOff[mi] = rowA * 32 + ((c ^ ((rowA >> 1) & 3)) << 3);
    int rowB = wc * 64 + mi * 16 + r;
    bOff[mi] = rowB * 32 + ((c ^ ((rowB >> 1) & 3)) << 3);
  }

  f32x4 acc[4][4];
#pragma unroll
  for (int mi = 0; mi < 4; mi++)
#pragma unroll
    for (int ni = 0; ni < 4; ni++) acc[mi][ni] = f32x4{0.f, 0.f, 0.f, 0.f};

#pragma unroll
  for (int i2 = 0; i2 < 2; i2++) {
    gload16(aSrc[i2], &lsA[0][dstOff[i2]]);
    gload16(bSrc[i2], &lsB[0][dstOff[i2]]);
  }

  auto compute = [&](const u16* pa, const u16* pb) {
    short8 af[4], bf[4];
#pragma unroll
    for (int mi = 0; mi < 4; mi++) af[mi] = *(const short8*)(pa + aOff[mi]);
#pragma unroll
    for (int ni = 0; ni < 4; ni++) bf[ni] = *(const short8*)(pb + bOff[ni]);
#pragma unroll
    for (int mi = 0; mi < 4; mi++)
#pragma unroll
      for (int ni = 0; ni < 4; ni++)
        acc[mi][ni] = MFMA_BF16(af[mi], bf[ni], acc[mi][ni]);
  };

  for (int kt = 0; kt < 31; kt++) {
    int cur = kt & 1;
    __syncthreads();
#pragma unroll
    for (int i2 = 0; i2 < 2; i2++) {
      gload16(aSrc[i2] + (kt + 1) * 32, &lsA[cur ^ 1][dstOff[i2]]);
      gload16(bSrc[i2] + (kt + 1) * 32, &lsB[cur ^ 1][dstOff[i2]]);
    }
    compute(lsA[cur], lsB[cur]);
  }
  __syncthreads();
  compute(lsA[1], lsB[1]);

  int h = n0 >> 6;
#pragma unroll
  for (int mi = 0; mi < 4; mi++) {
#pragma unroll
    for (int j = 0; j < 4; j++) {
      int grow = m0 + mi * 16 + c * 4 + j;
      int b = grow >> 11, ll = grow & 2047;
      if (z < 2) {
        u16* o = (z == 0) ? qo : ko;
        float lam = (z == 0) ? QLAMBDA : 1.0f;
        size_t dst = ((size_t)(b * NHEAD + h) * L + ll) * HD;
#pragma unroll
        for (int ni = 0; ni < 2; ni++) {
          int d = ni * 16 + r;  // 0..31
          float x1 = acc[mi][ni][j] + bias[n0 + d];
          float x2 = acc[mi][ni + 2][j] + bias[n0 + 32 + d];
          float cs = ct[ll * 32 + d], sn = st[ll * 32 + d];
          o[dst + d]      = f2bf((x1 * cs - x2 * sn) * lam);
          o[dst + d + 32] = f2bf((x2 * cs + x1 * sn) * lam);
        }
      } else {
#pragma unroll
        for (int ni = 0; ni < 4; ni++) {
          int d = ni * 16 + r;
          float val = acc[mi][ni][j] + bias[n0 + d];
          vT[((size_t)(b * NHEAD + h) * HD + d) * L + ll] = f2bf(val);
        }
      }
    }
  }
}

// ---------- fallback projection (f32 A direct from global), if ws too small ----------
__global__ __launch_bounds__(256) void proj_gemm_f32(
    const float* Qf, const float* Kf, const float* Vf, const u16* wT,
    const float* bq, const float* bk, const float* bv,
    const float* ct, const float* st,
    u16* qo, u16* ko, u16* vT) {
  int i = blockIdx.x;
  int swz = (i & 7) * 96 + (i >> 3);
  int z = swz >> 8;
  int bx = swz & 7;
  int by = (swz >> 3) & 31;

  const u16* W = wT + (size_t)z * D * D;
  const float* bias = z == 0 ? bq : z == 1 ? bk : bv;

  int w = threadIdx.x >> 6, lane = threadIdx.x & 63;
  int r = lane & 15, c = lane >> 4;
  int wr = w >> 1, wc = w & 1;
  int m0 = by * 128 + wr * 64;
  int n0 = bx * 128 + wc * 64;

  const float* Af = z == 0 ? Qf : z == 1 ? Kf : Vf;
  const float* a0f = Af + (size_t)(m0 + r) * D + c * 8;
  const u16* b0 = W + (size_t)(n0 + r) * D + c * 8;

  f32x4 acc[4][4];
#pragma unroll
  for (int mi = 0; mi < 4; mi++)
#pragma unroll
    for (int ni = 0; ni < 4; ni++) acc[mi][ni] = f32x4{0.f, 0.f, 0.f, 0.f};

  for (int kk = 0; kk < D; kk += 32) {
    short8 af[4], bf[4];
#pragma unroll
    for (int mi = 0; mi < 4; mi++) {
      const float* ap = a0f + (size_t)mi * 16 * D;
      af[mi] = cvt8(*(const f32x4*)ap, *(const f32x4*)(ap + 4));
    }
#pragma unroll
    for (int ni = 0; ni < 4; ni++) bf[ni] = *(const short8*)(b0 + (size_t)ni * 16 * D);
#pragma unroll
    for (int mi = 0; mi < 4; mi++)
#pragma unroll
      for (int ni = 0; ni < 4; ni++)
        acc[mi][ni] = MFMA_BF16(af[mi], bf[ni], acc[mi][ni]);
    a0f += 32;
    b0 += 32;
  }

  int h = n0 >> 6;
#pragma unroll
  for (int mi = 0; mi < 4; mi++) {
#pragma unroll
    for (int j = 0; j < 4; j++) {
      int grow = m0 + mi * 16 + c * 4 + j;
      int b = grow >> 11, ll = grow & 2047;
      if (z < 2) {
        u16* o = (z == 0) ? qo : ko;
        float lam = (z == 0) ? QLAMBDA : 1.0f;
        size_t dst = ((size_t)(b * NHEAD + h) * L + ll) * HD;
#pragma unroll
        for (int ni = 0; ni < 2; ni++) {
          int d = ni * 16 + r;
          float x1 = acc[mi][ni][j] + bias[n0 + d];
          float x2 = acc[mi][ni + 2][j] + bias[n0 + 32 + d];
          float cs = ct[ll * 32 + d], sn = st[ll * 32 + d];
          o[dst + d]      = f2bf((x1 * cs - x2 * sn) * lam);
          o[dst + d + 32] = f2bf((x2 * cs + x1 * sn) * lam);
        }
      } else {
#pragma unroll
        for (int ni = 0; ni < 4; ni++) {
          int d = ni * 16 + r;
          float val = acc[mi][ni][j] + bias[n0 + d];
          vT[((size_t)(b * NHEAD + h) * HD + d) * L + ll] = f2bf(val);
        }
      }
    }
  }
}

// ---------- causal flash attention, pair-balanced + shared K/V fragment reads ----------
// 512 blocks x 4 waves. Block = (head, q-tile pair (a, 31-a)). K/V LDS-staged
// double-buffered; when both tiles are active the K and V fragments are read
// from LDS ONCE and feed both tiles' MFMAs (LDS ops 36 -> 20 per iteration).
// Fixed-shift exp2 softmax, row-sum via ones-MFMA.
__global__ __launch_bounds__(256) void attn_kernel(const u16* qg, const u16* kg,
                                                   const u16* vg, u16* O) {
  int i = blockIdx.x;
  int xcd = i & 7, j = i >> 3;        // j in [0,64)
  int bh = xcd * 4 + (j & 3);         // 4 heads per XCD -> K/V L2 affinity
  int a = j >> 2;                     // pair index in [0,16)
  int qtA = a, qtB = 31 - a;          // 64-row tiles; B is the heavy one

  int w = threadIdx.x >> 6, lane = threadIdx.x & 63;
  int r = lane & 15, c = lane >> 4;
  int qbA = qtA * 64 + w * 16;
  int qbB = qtB * 64 + w * 16;

  const u16* qp = qg + (size_t)bh * L * HD;
  const u16* kp = kg + (size_t)bh * L * HD;
  const u16* vp = vg + (size_t)bh * HD * L;

  __shared__ __align__(16) u16 kls[2][4096];
  __shared__ __align__(16) u16 vls[2][4096];
  __shared__ __align__(16) u16 plds[4][2][16][64];

  short8 aqA0 = *(const short8*)(qp + (size_t)(qbA + r) * HD + c * 8);
  short8 aqA1 = *(const short8*)(qp + (size_t)(qbA + r) * HD + 32 + c * 8);
  short8 aqB0 = *(const short8*)(qp + (size_t)(qbB + r) * HD + c * 8);
  short8 aqB1 = *(const short8*)(qp + (size_t)(qbB + r) * HD + 32 + c * 8);

  const short one_bf = (short)0x3F80;
  short8 ones = {one_bf, one_bf, one_bf, one_bf, one_bf, one_bf, one_bf, one_bf};

  f32x4 oA[4], oB[4];
  f32x4 sacA = f32x4{0.f, 0.f, 0.f, 0.f};
  f32x4 sacB = f32x4{0.f, 0.f, 0.f, 0.f};
#pragma unroll
  for (int n = 0; n < 4; n++) {
    oA[n] = f32x4{0.f, 0.f, 0.f, 0.f};
    oB[n] = f32x4{0.f, 0.f, 0.f, 0.f};
  }

  int nkt = qtB + 1;  // = 32 - a >= 17

  // prologue: stage tile 0
#pragma unroll
  for (int rd = 0; rd < 2; rd++) {
    int q0 = (rd * 4 + w) << 6;
    int qq = q0 + lane;
    int row = qq >> 3;
    int gch = (qq & 7) ^ (row & 7);
    gload16(kp + (size_t)row * HD + gch * 8, &kls[0][q0 * 8]);
    gload16(vp + (size_t)row * L + gch * 8, &vls[0][q0 * 8]);
  }

  for (int kt = 0; kt < nkt; kt++) {
    int cur = kt & 1;
    __syncthreads();  // drains vmcnt: stage of buf[cur] complete
    if (kt + 1 < nkt) {
      int kb2 = (kt + 1) * 64;
      const u16* kp2 = kp + (size_t)kb2 * HD;
      const u16* vp2 = vp + kb2;
#pragma unroll
      for (int rd = 0; rd < 2; rd++) {
        int q0 = (rd * 4 + w) << 6;
        int qq = q0 + lane;
        int row = qq >> 3;
        int gch = (qq & 7) ^ (row & 7);
        gload16(kp2 + (size_t)row * HD + gch * 8, &kls[cur ^ 1][q0 * 8]);
        gload16(vp2 + (size_t)row * L + gch * 8, &vls[cur ^ 1][q0 * 8]);
      }
    }
    const u16* kb_ = kls[cur];
    const u16* vb_ = vls[cur];
    int kbase = kt * 64;
    bool actA = (kt <= qtA);

    // --- QK^T: shared K fragment reads feed both tiles ---
    f32x4 SB[4], SA[4];
#pragma unroll
    for (int ks = 0; ks < 4; ks++) {
      int row = ks * 16 + r;
      short8 kf0 = *(const short8*)(kb_ + row * 64 + ((c ^ (row & 7)) << 3));
      short8 kf1 = *(const short8*)(kb_ + row * 64 + (((4 + c) ^ (row & 7)) << 3));
      SB[ks] = f32x4{0.f, 0.f, 0.f, 0.f};
      SB[ks] = MFMA_BF16(aqB0, kf0, SB[ks]);
      SB[ks] = MFMA_BF16(aqB1, kf1, SB[ks]);
      if (actA) {
        SA[ks] = f32x4{0.f, 0.f, 0.f, 0.f};
        SA[ks] = MFMA_BF16(aqA0, kf0, SA[ks]);
        SA[ks] = MFMA_BF16(aqA1, kf1, SA[ks]);
      }
    }

    // --- softmax (fixed-shift exp2) + P write, per tile ---
    bool edgeB = (kt == nkt - 1);
#pragma unroll
    for (int j4 = 0; j4 < 4; j4++) {
      float p0 = exp2f(SB[0][j4]);
      float p1 = exp2f(SB[1][j4]);
      float p2 = exp2f(SB[2][j4]);
      float p3 = exp2f(SB[3][j4]);
      if (edgeB) {
        int qrow = qbB + c * 4 + j4;
        if (kbase + r > qrow) p0 = 0.f;
        if (kbase + 16 + r > qrow) p1 = 0.f;
        if (kbase + 32 + r > qrow) p2 = 0.f;
        if (kbase + 48 + r > qrow) p3 = 0.f;
      }
      int prow = c * 4 + j4, xr = (prow & 7) << 3;
      plds[w][0][prow][(r) ^ xr]      = f2bf(p0);
      plds[w][0][prow][(16 + r) ^ xr] = f2bf(p1);
      plds[w][0][prow][(32 + r) ^ xr] = f2bf(p2);
      plds[w][0][prow][(48 + r) ^ xr] = f2bf(p3);
    }
    if (actA) {
      bool edgeA = (kt == qtA);
#pragma unroll
      for (int j4 = 0; j4 < 4; j4++) {
        float p0 = exp2f(SA[0][j4]);
        float p1 = exp2f(SA[1][j4]);
        float p2 = exp2f(SA[2][j4]);
        float p3 = exp2f(SA[3][j4]);
        if (edgeA) {
          int qrow = qbA + c * 4 + j4;
          if (kbase + r > qrow) p0 = 0.f;
          if (kbase + 16 + r > qrow) p1 = 0.f;
          if (kbase + 32 + r > qrow) p2 = 0.f;
          if (kbase + 48 + r > qrow) p3 = 0.f;
        }
        int prow = c * 4 + j4, xr = (prow & 7) << 3;
        plds[w][1][prow][(r) ^ xr]      = f2bf(p0);
        plds[w][1][prow][(16 + r) ^ xr] = f2bf(p1);
        plds[w][1][prow][(32 + r) ^ xr] = f2bf(p2);
        plds[w][1][prow][(48 + r) ^ xr] = f2bf(p3);
      }
    }

    // --- PV: shared V fragment reads feed both tiles ---
    int xrr = (r & 7) << 3;
    short8 paB0 = *(const short8*)&plds[w][0][r][(c * 8) ^ xrr];
    short8 paB1 = *(const short8*)&plds[w][0][r][(32 + c * 8) ^ xrr];
    sacB = MFMA_BF16(paB0, ones, sacB);
    sacB = MFMA_BF16(paB1, ones, sacB);
    short8 paA0, paA1;
    if (actA) {
      paA0 = *(const short8*)&plds[w][1][r][(c * 8) ^ xrr];
      paA1 = *(const short8*)&plds[w][1][r][(32 + c * 8) ^ xrr];
      sacA = MFMA_BF16(paA0, ones, sacA);
      sacA = MFMA_BF16(paA1, ones, sacA);
    }
#pragma unroll
    for (int n = 0; n < 4; n++) {
      int row = n * 16 + r;
      short8 vf0 = *(const short8*)(vb_ + row * 64 + ((c ^ (row & 7)) << 3));
      short8 vf1 = *(const short8*)(vb_ + row * 64 + (((4 + c) ^ (row & 7)) << 3));
      oB[n] = MFMA_BF16(paB0, vf0, oB[n]);
      oB[n] = MFMA_BF16(paB1, vf1, oB[n]);
      if (actA) {
        oA[n] = MFMA_BF16(paA0, vf0, oA[n]);
        oA[n] = MFMA_BF16(paA1, vf1, oA[n]);
      }
    }
  }

  int b = bh >> 4, h = bh & 15;
#pragma unroll
  for (int j4 = 0; j4 < 4; j4++) {
    int qrowA = qbA + c * 4 + j4;
    int qrowB = qbB + c * 4 + j4;
    float invA = 1.0f / sacA[j4];
    float invB = 1.0f / sacB[j4];
#pragma unroll
    for (int n = 0; n < 4; n++) {
      O[((size_t)(b * L + qrowA)) * D + h * HD + n * 16 + r] = f2bf(oA[n][j4] * invA);
      O[((size_t)(b * L + qrowB)) * D + h * HD + n * 16 + r] = f2bf(oB[n][j4] * invB);
    }
  }
}

// ---------- output projection (staged), f32 out + bias ----------
__global__ __launch_bounds__(256, 3) void oproj_gemm_staged(const u16* Ag, const u16* wT,
                                                            const float* bias, float* out) {
  int i = blockIdx.x;  // 256 blocks
  int swz = (i & 7) * 32 + (i >> 3);
  int bx = swz & 7, by = swz >> 3;

  int w = threadIdx.x >> 6, lane = threadIdx.x & 63;
  int r = lane & 15, c = lane >> 4;
  int wr = w >> 1, wc = w & 1;
  int m0 = by * 128 + wr * 64;
  int n0 = bx * 128 + wc * 64;

  __shared__ __align__(16) u16 lsA[2][4096];
  __shared__ __align__(16) u16 lsB[2][4096];

  const u16* aSrc[2];
  const u16* bSrc[2];
  int dstOff[2];
#pragma unroll
  for (int i2 = 0; i2 < 2; i2++) {
    int q0 = i2 * 256 + w * 64;
    int qq = q0 + lane;
    int t = qq >> 2;
    int gch = (qq & 3) ^ ((t >> 1) & 3);
    aSrc[i2] = Ag + (size_t)(by * 128 + t) * D + gch * 8;
    bSrc[i2] = wT + (size_t)(bx * 128 + t) * D + gch * 8;
    dstOff[i2] = q0 * 8;
  }

  int aOff[4], bOff[4];
#pragma unroll
  for (int mi = 0; mi < 4; mi++) {
    int rowA = wr * 64 + mi * 16 + r;
    aOff[mi] = rowA * 32 + ((c ^ ((rowA >> 1) & 3)) << 3);
    int rowB = wc * 64 + mi * 16 + r;
    bOff[mi] = rowB * 32 + ((c ^ ((rowB >> 1) & 3)) << 3);
  }

  f32x4 acc[4][4];
#pragma unroll
  for (int mi = 0; mi < 4; mi++)
#pragma unroll
    for (int ni = 0; ni < 4; ni++) acc[mi][ni] = f32x4{0.f, 0.f, 0.f, 0.f};

#pragma unroll
  for (int i2 = 0; i2 < 2; i2++) {
    gload16(aSrc[i2], &lsA[0][dstOff[i2]]);
    gload16(bSrc[i2], &lsB[0][dstOff[i2]]);
  }

  auto compute = [&](const u16* pa, const u16* pb) {
    short8 af[4], bf[4];
#pragma unroll
    for (int mi = 0; mi < 4; mi++) af[mi] = *(const short8*)(pa + aOff[mi]);
#pragma unroll
    for (int ni = 0; ni < 4; ni++) bf[ni] = *(const short8*)(pb + bOff[ni]);
#pragma unroll
    for (int mi = 0; mi < 4; mi++)
#pragma unroll
      for (int ni = 0; ni < 4; ni++)
        acc[mi][ni] = MFMA_BF16(af[mi], bf[ni], acc[mi][ni]);
  };

  for (int kt = 0; kt < 31; kt++) {
    int cur = kt & 1;
    __syncthreads();
#pragma unroll
    for (int i2 = 0; i2 < 2; i2++) {
      gload16(aSrc[i2] + (kt + 1) * 32, &lsA[cur ^ 1][dstOff[i2]]);
      gload16(bSrc[i2] + (kt + 1) * 32, &lsB[cur ^ 1][dstOff[i2]]);
    }
    compute(lsA[cur], lsB[cur]);
  }
  __syncthreads();
  compute(lsA[1], lsB[1]);

#pragma unroll
  for (int mi = 0; mi < 4; mi++)
#pragma unroll
    for (int j = 0; j < 4; j++) {
      int grow = m0 + mi * 16 + c * 4 + j;
#pragma unroll
      for (int ni = 0; ni < 4; ni++) {
        int gcol = n0 + ni * 16 + r;
        out[(size_t)grow * D + gcol] = acc[mi][ni][j] + bias[gcol];
      }
    }
}

extern "C" void kernel_launch(void* const* d_in, const int* in_sizes, int n_in,
                              void* d_out, int out_size, void* d_ws, size_t ws_size,
                              hipStream_t stream) {
  const float* Q = (const float*)d_in[0];
  const float* K = (const float*)d_in[1];
  const float* V = (const float*)d_in[2];
  const float* Wq = (const float*)d_in[3];
  const float* Wk = (const float*)d_in[4];
  const float* Wv = (const float*)d_in[5];
  const float* Wo = (const float*)d_in[6];
  const float* bq = (const float*)d_in[7];
  const float* bk = (const float*)d_in[8];
  const float* bv = (const float*)d_in[9];
  const float* bo = (const float*)d_in[10];
  float* out = (float*)d_out;

  char* ws = (char*)d_ws;
  u16* wT = (u16*)(ws);
  u16* woT = wT + (size_t)3 * 1024 * 1024;
  float* ct = (float*)(ws + 8388608);
  float* st = (float*)(ws + 8650752);
  u16* qbuf = (u16*)(ws + 8912896);
  u16* kbuf = (u16*)(ws + 17301504);
  u16* vbuf = (u16*)(ws + 25690112);
  u16* obuf = (u16*)(ws + 34078720);
  u16* xb = (u16*)(ws + 42467328);

  if (ws_size >= (size_t)67633152) {
    prep_kernel<true><<<dim3(10496), 256, 0, stream>>>(Wq, Wk, Wv, Wo, wT, ct, st,
                                                       Q, K, V, xb);
    proj_gemm_staged<<<dim3(768), 256, 0, stream>>>(xb, wT, bq, bk, bv, ct, st,
                                                    qbuf, kbuf, vbuf);
  } else {
    prep_kernel<false><<<dim3(4352), 256, 0, stream>>>(Wq, Wk, Wv, Wo, wT, ct, st,
                                                       Q, K, V, xb);
    proj_gemm_f32<<<dim3(768), 256, 0, stream>>>(Q, K, V, wT, bq, bk, bv, ct, st,
                                                 qbuf, kbuf, vbuf);
  }
  attn_kernel<<<dim3(512), 256, 0, stream>>>(qbuf, kbuf, vbuf, obuf);
  oproj_gemm_staged<<<dim3(256), 256, 0, stream>>>(obuf, woT, bo, out);
}

// Round 8
// 255.957 us; speedup vs baseline: 1.0531x; 1.0531x over previous
//
#include <hip/hip_runtime.h>

typedef __attribute__((ext_vector_type(8))) short short8;
typedef __attribute__((ext_vector_type(4))) float f32x4;
typedef unsigned short u16;
typedef unsigned int u32;

#define MFMA_BF16(a, b, c) __builtin_amdgcn_mfma_f32_16x16x32_bf16((a), (b), (c), 0, 0, 0)

constexpr int D = 1024;
constexpr int L = 2048;
constexpr int NHEAD = 16;
constexpr int HD = 64;
// fold softmax scale (1/8) and log2(e) into q at projection time
constexpr float QLAMBDA = 0.125f * 1.44269504088896340736f;

__device__ __forceinline__ u16 f2bf(float f) {
  unsigned u = __builtin_bit_cast(unsigned, f);
  u = (u + 0x7fffu + ((u >> 16) & 1u)) >> 16;
  return (u16)u;
}

// hardware bf16 convert (RNE), 1 VALU inst (no builtin on gfx950 -- inline asm)
__device__ __forceinline__ u16 cvt1(float f) {
  unsigned o;
  asm("v_cvt_pk_bf16_f32 %0, %1, %1" : "=v"(o) : "v"(f));
  return (u16)o;
}

__device__ __forceinline__ short8 cvt8(f32x4 lo, f32x4 hi) {
  short8 r;
  r[0] = (short)f2bf(lo[0]); r[1] = (short)f2bf(lo[1]);
  r[2] = (short)f2bf(lo[2]); r[3] = (short)f2bf(lo[3]);
  r[4] = (short)f2bf(hi[0]); r[5] = (short)f2bf(hi[1]);
  r[6] = (short)f2bf(hi[2]); r[7] = (short)f2bf(hi[3]);
  return r;
}

// async global->LDS, 16B per lane. dst must be wave-uniform; per-lane global src.
__device__ __forceinline__ void gload16(const u16* src, u16* dst) {
  __builtin_amdgcn_global_load_lds(
      (const __attribute__((address_space(1))) u32*)(src),
      (__attribute__((address_space(3))) u32*)(dst), 16, 0, 0);
}

// ---------- merged prep: weight transpose | RoPE tables | X f32->bf16 ----------
template <bool DO_CVT>
__global__ __launch_bounds__(256) void prep_kernel(
    const float* W0, const float* W1, const float* W2, const float* W3, u16* wTout,
    float* ct, float* st,
    const float* Q, const float* K, const float* V, u16* xb) {
  int i = blockIdx.x;
  if (i < 4096) {
    int z = i >> 10, bx = i & 31, by = (i >> 5) & 31;
    const float* W = z == 0 ? W0 : z == 1 ? W1 : z == 2 ? W2 : W3;
    u16* o = wTout + (size_t)z * D * D;
    __shared__ float t[32][33];
    int x = threadIdx.x & 31, y = threadIdx.x >> 5;
    int k0 = bx * 32, n0 = by * 32;
#pragma unroll
    for (int q = 0; q < 4; q++) {
      int ky = y * 4 + q;
      t[ky][x] = W[(size_t)(k0 + ky) * D + n0 + x];
    }
    __syncthreads();
#pragma unroll
    for (int q = 0; q < 4; q++) {
      int ny = y * 4 + q;
      o[(size_t)(n0 + ny) * D + k0 + x] = f2bf(t[x][ny]);
    }
  } else if (i < 4352) {
    int t = (i - 4096) * 256 + threadIdx.x;  // L*32 = 65536
    int ii = t & 31, pos = t >> 5;
    float invf = powf(10000.0f, -(float)ii / 32.0f);
    float ang = (float)pos * invf;
    ct[t] = cosf(ang);
    st[t] = sinf(ang);
  } else if constexpr (DO_CVT) {
    int j = i - 4352;
    int zz = j / 2048, bx = j - zz * 2048;
    const float* src = zz == 0 ? Q : zz == 1 ? K : V;
    u16* dst = xb + (size_t)zz * 4096 * D;
    int t = bx * 256 + threadIdx.x;
    const float* p = src + (size_t)t * 8;
    f32x4 lo = *(const f32x4*)p;
    f32x4 hi = *(const f32x4*)(p + 4);
    *(short8*)(dst + (size_t)t * 8) = cvt8(lo, hi);
  }
}

// ======== staged GEMM core (128x128 tile, BK=32, LDS dbuf, gload_lds) ========

// ---------- fused QKV projection GEMM + bias + RoPE epilogue ----------
__global__ __launch_bounds__(256, 3) void proj_gemm_staged(
    const u16* xb, const u16* wT,
    const float* bq, const float* bk, const float* bv,
    const float* ct, const float* st,
    u16* qo, u16* ko, u16* vT) {
  int i = blockIdx.x;  // 768 blocks, bijective XCD swizzle (768%8==0)
  int swz = (i & 7) * 96 + (i >> 3);
  int z = swz >> 8;
  int bx = swz & 7;
  int by = (swz >> 3) & 31;

  const u16* A = xb + (size_t)z * 4096 * D;
  const u16* W = wT + (size_t)z * D * D;
  const float* bias = z == 0 ? bq : z == 1 ? bk : bv;

  int w = threadIdx.x >> 6, lane = threadIdx.x & 63;
  int r = lane & 15, c = lane >> 4;
  int wr = w >> 1, wc = w & 1;
  int m0 = by * 128 + wr * 64;
  int n0 = bx * 128 + wc * 64;

  __shared__ __align__(16) u16 lsA[2][4096];
  __shared__ __align__(16) u16 lsB[2][4096];

  const u16* aSrc[2];
  const u16* bSrc[2];
  int dstOff[2];
#pragma unroll
  for (int i2 = 0; i2 < 2; i2++) {
    int q0 = i2 * 256 + w * 64;
    int qq = q0 + lane;
    int t = qq >> 2;
    int gch = (qq & 3) ^ ((t >> 1) & 3);
    aSrc[i2] = A + (size_t)(by * 128 + t) * D + gch * 8;
    bSrc[i2] = W + (size_t)(bx * 128 + t) * D + gch * 8;
    dstOff[i2] = q0 * 8;
  }

  int aOff[4], bOff[4];
#pragma unroll
  for (int mi = 0; mi < 4; mi++) {
    int rowA = wr * 64 + mi * 16 + r;
    aOff[mi] = rowA * 32 + ((c ^ ((rowA >> 1) & 3)) << 3);
    int rowB = wc * 64 + mi * 16 + r;
    bOff[mi] = rowB * 32 + ((c ^ ((rowB >> 1) & 3)) << 3);
  }

  f32x4 acc[4][4];
#pragma unroll
  for (int mi = 0; mi < 4; mi++)
#pragma unroll
    for (int ni = 0; ni < 4; ni++) acc[mi][ni] = f32x4{0.f, 0.f, 0.f, 0.f};

#pragma unroll
  for (int i2 = 0; i2 < 2; i2++) {
    gload16(aSrc[i2], &lsA[0][dstOff[i2]]);
    gload16(bSrc[i2], &lsB[0][dstOff[i2]]);
  }

  auto compute = [&](const u16* pa, const u16* pb) {
    short8 af[4], bf[4];
#pragma unroll
    for (int mi = 0; mi < 4; mi++) af[mi] = *(const short8*)(pa + aOff[mi]);
#pragma unroll
    for (int ni = 0; ni < 4; ni++) bf[ni] = *(const short8*)(pb + bOff[ni]);
#pragma unroll
    for (int mi = 0; mi < 4; mi++)
#pragma unroll
      for (int ni = 0; ni < 4; ni++)
        acc[mi][ni] = MFMA_BF16(af[mi], bf[ni], acc[mi][ni]);
  };

  for (int kt = 0; kt < 31; kt++) {
    int cur = kt & 1;
    __syncthreads();
#pragma unroll
    for (int i2 = 0; i2 < 2; i2++) {
      gload16(aSrc[i2] + (kt + 1) * 32, &lsA[cur ^ 1][dstOff[i2]]);
      gload16(bSrc[i2] + (kt + 1) * 32, &lsB[cur ^ 1][dstOff[i2]]);
    }
    compute(lsA[cur], lsB[cur]);
  }
  __syncthreads();
  compute(lsA[1], lsB[1]);

  int h = n0 >> 6;
#pragma unroll
  for (int mi = 0; mi < 4; mi++) {
#pragma unroll
    for (int j = 0; j < 4; j++) {
      int grow = m0 + mi * 16 + c * 4 + j;
      int b = grow >> 11, ll = grow & 2047;
      if (z < 2) {
        u16* o = (z == 0) ? qo : ko;
        float lam = (z == 0) ? QLAMBDA : 1.0f;
        size_t dst = ((size_t)(b * NHEAD + h) * L + ll) * HD;
#pragma unroll
        for (int ni = 0; ni < 2; ni++) {
          int d = ni * 16 + r;  // 0..31
          float x1 = acc[mi][ni][j] + bias[n0 + d];
          float x2 = acc[mi][ni + 2][j] + bias[n0 + 32 + d];
          float cs = ct[ll * 32 + d], sn = st[ll * 32 + d];
          o[dst + d]      = cvt1((x1 * cs - x2 * sn) * lam);
          o[dst + d + 32] = cvt1((x2 * cs + x1 * sn) * lam);
        }
      } else {
#pragma unroll
        for (int ni = 0; ni < 4; ni++) {
          int d = ni * 16 + r;
          float val = acc[mi][ni][j] + bias[n0 + d];
          vT[((size_t)(b * NHEAD + h) * HD + d) * L + ll] = cvt1(val);
        }
      }
    }
  }
}

// ---------- fallback projection (f32 A direct from global), if ws too small ----------
__global__ __launch_bounds__(256) void proj_gemm_f32(
    const float* Qf, const float* Kf, const float* Vf, const u16* wT,
    const float* bq, const float* bk, const float* bv,
    const float* ct, const float* st,
    u16* qo, u16* ko, u16* vT) {
  int i = blockIdx.x;
  int swz = (i & 7) * 96 + (i >> 3);
  int z = swz >> 8;
  int bx = swz & 7;
  int by = (swz >> 3) & 31;

  const u16* W = wT + (size_t)z * D * D;
  const float* bias = z == 0 ? bq : z == 1 ? bk : bv;

  int w = threadIdx.x >> 6, lane = threadIdx.x & 63;
  int r = lane & 15, c = lane >> 4;
  int wr = w >> 1, wc = w & 1;
  int m0 = by * 128 + wr * 64;
  int n0 = bx * 128 + wc * 64;

  const float* Af = z == 0 ? Qf : z == 1 ? Kf : Vf;
  const float* a0f = Af + (size_t)(m0 + r) * D + c * 8;
  const u16* b0 = W + (size_t)(n0 + r) * D + c * 8;

  f32x4 acc[4][4];
#pragma unroll
  for (int mi = 0; mi < 4; mi++)
#pragma unroll
    for (int ni = 0; ni < 4; ni++) acc[mi][ni] = f32x4{0.f, 0.f, 0.f, 0.f};

  for (int kk = 0; kk < D; kk += 32) {
    short8 af[4], bf[4];
#pragma unroll
    for (int mi = 0; mi < 4; mi++) {
      const float* ap = a0f + (size_t)mi * 16 * D;
      af[mi] = cvt8(*(const f32x4*)ap, *(const f32x4*)(ap + 4));
    }
#pragma unroll
    for (int ni = 0; ni < 4; ni++) bf[ni] = *(const short8*)(b0 + (size_t)ni * 16 * D);
#pragma unroll
    for (int mi = 0; mi < 4; mi++)
#pragma unroll
      for (int ni = 0; ni < 4; ni++)
        acc[mi][ni] = MFMA_BF16(af[mi], bf[ni], acc[mi][ni]);
    a0f += 32;
    b0 += 32;
  }

  int h = n0 >> 6;
#pragma unroll
  for (int mi = 0; mi < 4; mi++) {
#pragma unroll
    for (int j = 0; j < 4; j++) {
      int grow = m0 + mi * 16 + c * 4 + j;
      int b = grow >> 11, ll = grow & 2047;
      if (z < 2) {
        u16* o = (z == 0) ? qo : ko;
        float lam = (z == 0) ? QLAMBDA : 1.0f;
        size_t dst = ((size_t)(b * NHEAD + h) * L + ll) * HD;
#pragma unroll
        for (int ni = 0; ni < 2; ni++) {
          int d = ni * 16 + r;
          float x1 = acc[mi][ni][j] + bias[n0 + d];
          float x2 = acc[mi][ni + 2][j] + bias[n0 + 32 + d];
          float cs = ct[ll * 32 + d], sn = st[ll * 32 + d];
          o[dst + d]      = cvt1((x1 * cs - x2 * sn) * lam);
          o[dst + d + 32] = cvt1((x2 * cs + x1 * sn) * lam);
        }
      } else {
#pragma unroll
        for (int ni = 0; ni < 4; ni++) {
          int d = ni * 16 + r;
          float val = acc[mi][ni][j] + bias[n0 + d];
          vT[((size_t)(b * NHEAD + h) * HD + d) * L + ll] = cvt1(val);
        }
      }
    }
  }
}

// ---------- causal flash attention, pair-balanced (R6 structure + hw cvt) ----------
// 512 blocks x 4 waves. Block = (head, q-tile pair (a, 31-a)) -> 33 K-tile
// computes per block, exactly uniform. K/V LDS-staged double-buffered,
// fixed-shift exp2 softmax, row-sum via ones-MFMA, v_cvt_pk_bf16_f32 for P.
__global__ __launch_bounds__(256) void attn_kernel(const u16* qg, const u16* kg,
                                                   const u16* vg, u16* O) {
  int i = blockIdx.x;
  int xcd = i & 7, j = i >> 3;        // j in [0,64)
  int bh = xcd * 4 + (j & 3);         // 4 heads per XCD -> K/V L2 affinity
  int a = j >> 2;                     // pair index in [0,16)
  int qtA = a, qtB = 31 - a;          // 64-row tiles; B is the heavy one

  int w = threadIdx.x >> 6, lane = threadIdx.x & 63;
  int r = lane & 15, c = lane >> 4;
  int qbA = qtA * 64 + w * 16;
  int qbB = qtB * 64 + w * 16;

  const u16* qp = qg + (size_t)bh * L * HD;
  const u16* kp = kg + (size_t)bh * L * HD;
  const u16* vp = vg + (size_t)bh * HD * L;

  __shared__ __align__(16) u16 kls[2][4096];
  __shared__ __align__(16) u16 vls[2][4096];
  __shared__ __align__(16) u16 plds[4][16][64];

  short8 aqA0 = *(const short8*)(qp + (size_t)(qbA + r) * HD + c * 8);
  short8 aqA1 = *(const short8*)(qp + (size_t)(qbA + r) * HD + 32 + c * 8);
  short8 aqB0 = *(const short8*)(qp + (size_t)(qbB + r) * HD + c * 8);
  short8 aqB1 = *(const short8*)(qp + (size_t)(qbB + r) * HD + 32 + c * 8);

  const short one_bf = (short)0x3F80;
  short8 ones = {one_bf, one_bf, one_bf, one_bf, one_bf, one_bf, one_bf, one_bf};

  f32x4 oA[4], oB[4];
  f32x4 sacA = f32x4{0.f, 0.f, 0.f, 0.f};
  f32x4 sacB = f32x4{0.f, 0.f, 0.f, 0.f};
#pragma unroll
  for (int n = 0; n < 4; n++) {
    oA[n] = f32x4{0.f, 0.f, 0.f, 0.f};
    oB[n] = f32x4{0.f, 0.f, 0.f, 0.f};
  }

  int nkt = qtB + 1;  // = 32 - a >= 17

  // prologue: stage tile 0
#pragma unroll
  for (int rd = 0; rd < 2; rd++) {
    int q0 = (rd * 4 + w) << 6;
    int qq = q0 + lane;
    int row = qq >> 3;
    int gch = (qq & 7) ^ (row & 7);
    gload16(kp + (size_t)row * HD + gch * 8, &kls[0][q0 * 8]);
    gload16(vp + (size_t)row * L + gch * 8, &vls[0][q0 * 8]);
  }

  for (int kt = 0; kt < nkt; kt++) {
    int cur = kt & 1;
    __syncthreads();  // drains vmcnt: stage of buf[cur] complete
    if (kt + 1 < nkt) {
      int kb2 = (kt + 1) * 64;
      const u16* kp2 = kp + (size_t)kb2 * HD;
      const u16* vp2 = vp + kb2;
#pragma unroll
      for (int rd = 0; rd < 2; rd++) {
        int q0 = (rd * 4 + w) << 6;
        int qq = q0 + lane;
        int row = qq >> 3;
        int gch = (qq & 7) ^ (row & 7);
        gload16(kp2 + (size_t)row * HD + gch * 8, &kls[cur ^ 1][q0 * 8]);
        gload16(vp2 + (size_t)row * L + gch * 8, &vls[cur ^ 1][q0 * 8]);
      }
    }
    const u16* kb_ = kls[cur];
    const u16* vb_ = vls[cur];
    int kbase = kt * 64;

    auto do_tile = [&](const short8& qf0, const short8& qf1, f32x4* o, f32x4& sac,
                       int qb, bool edge) {
      f32x4 S[4];
#pragma unroll
      for (int ks = 0; ks < 4; ks++) {
        int row = ks * 16 + r;
        short8 kf0 = *(const short8*)(kb_ + row * 64 + ((c ^ (row & 7)) << 3));
        short8 kf1 = *(const short8*)(kb_ + row * 64 + (((4 + c) ^ (row & 7)) << 3));
        S[ks] = f32x4{0.f, 0.f, 0.f, 0.f};
        S[ks] = MFMA_BF16(qf0, kf0, S[ks]);
        S[ks] = MFMA_BF16(qf1, kf1, S[ks]);
      }
#pragma unroll
      for (int j4 = 0; j4 < 4; j4++) {
        float p0 = exp2f(S[0][j4]);
        float p1 = exp2f(S[1][j4]);
        float p2 = exp2f(S[2][j4]);
        float p3 = exp2f(S[3][j4]);
        if (edge) {
          int qrow = qb + c * 4 + j4;
          if (kbase + r > qrow) p0 = 0.f;
          if (kbase + 16 + r > qrow) p1 = 0.f;
          if (kbase + 32 + r > qrow) p2 = 0.f;
          if (kbase + 48 + r > qrow) p3 = 0.f;
        }
        int prow = c * 4 + j4, xr = (prow & 7) << 3;
        plds[w][prow][(r) ^ xr]      = cvt1(p0);
        plds[w][prow][(16 + r) ^ xr] = cvt1(p1);
        plds[w][prow][(32 + r) ^ xr] = cvt1(p2);
        plds[w][prow][(48 + r) ^ xr] = cvt1(p3);
      }
      int xrr = (r & 7) << 3;
      short8 pa0 = *(const short8*)&plds[w][r][(c * 8) ^ xrr];
      short8 pa1 = *(const short8*)&plds[w][r][(32 + c * 8) ^ xrr];
      sac = MFMA_BF16(pa0, ones, sac);
      sac = MFMA_BF16(pa1, ones, sac);
#pragma unroll
      for (int n = 0; n < 4; n++) {
        int row = n * 16 + r;
        short8 vf0 = *(const short8*)(vb_ + row * 64 + ((c ^ (row & 7)) << 3));
        short8 vf1 = *(const short8*)(vb_ + row * 64 + (((4 + c) ^ (row & 7)) << 3));
        o[n] = MFMA_BF16(pa0, vf0, o[n]);
        o[n] = MFMA_BF16(pa1, vf1, o[n]);
      }
    };

    // heavy tile B: active every iteration; edge only on the last
    do_tile(aqB0, aqB1, oB, sacB, qbB, kt == nkt - 1);
    // light tile A: active while kt <= a; edge at kt == a
    if (kt <= qtA) do_tile(aqA0, aqA1, oA, sacA, qbA, kt == qtA);
  }

  int b = bh >> 4, h = bh & 15;
#pragma unroll
  for (int j4 = 0; j4 < 4; j4++) {
    int qrowA = qbA + c * 4 + j4;
    int qrowB = qbB + c * 4 + j4;
    float invA = 1.0f / sacA[j4];
    float invB = 1.0f / sacB[j4];
#pragma unroll
    for (int n = 0; n < 4; n++) {
      O[((size_t)(b * L + qrowA)) * D + h * HD + n * 16 + r] = cvt1(oA[n][j4] * invA);
      O[((size_t)(b * L + qrowB)) * D + h * HD + n * 16 + r] = cvt1(oB[n][j4] * invB);
    }
  }
}

// ---------- output projection (64x128 tile, 512 blocks = 2/CU), f32 out + bias ----------
__global__ __launch_bounds__(256) void oproj_gemm_staged(const u16* Ag, const u16* wT,
                                                         const float* bias, float* out) {
  int i = blockIdx.x;  // 512 blocks, bijective XCD swizzle (512%8==0)
  int swz = (i & 7) * 64 + (i >> 3);
  int bx = swz & 7, by = swz >> 3;  // bx: N tile (128), by: M tile (64)

  int w = threadIdx.x >> 6, lane = threadIdx.x & 63;
  int r = lane & 15, c = lane >> 4;
  int wr = w >> 1, wc = w & 1;
  int m0 = by * 64 + wr * 32;
  int n0 = bx * 128 + wc * 64;

  __shared__ __align__(16) u16 lsA[2][2048];  // 64 rows x 32 k
  __shared__ __align__(16) u16 lsB[2][4096];  // 128 rows x 32 k

  // A staging: 1 gload/thread (64x32 = 4KB/buffer)
  int qqA = w * 64 + lane;
  int tA = qqA >> 2;
  int gchA = (qqA & 3) ^ ((tA >> 1) & 3);
  const u16* aSrc = Ag + (size_t)(by * 64 + tA) * D + gchA * 8;
  int aDst = (w * 64) * 8;

  // B staging: 2 gloads/thread (128x32 = 8KB/buffer)
  const u16* bSrc[2];
  int bDst[2];
#pragma unroll
  for (int i2 = 0; i2 < 2; i2++) {
    int q0 = i2 * 256 + w * 64;
    int qq = q0 + lane;
    int t = qq >> 2;
    int gch = (qq & 3) ^ ((t >> 1) & 3);
    bSrc[i2] = wT + (size_t)(bx * 128 + t) * D + gch * 8;
    bDst[i2] = q0 * 8;
  }

  int aOff[2], bOff[4];
#pragma unroll
  for (int mi = 0; mi < 2; mi++) {
    int rowA = wr * 32 + mi * 16 + r;
    aOff[mi] = rowA * 32 + ((c ^ ((rowA >> 1) & 3)) << 3);
  }
#pragma unroll
  for (int ni = 0; ni < 4; ni++) {
    int rowB = wc * 64 + ni * 16 + r;
    bOff[ni] = rowB * 32 + ((c ^ ((rowB >> 1) & 3)) << 3);
  }

  f32x4 acc[2][4];
#pragma unroll
  for (int mi = 0; mi < 2; mi++)
#pragma unroll
    for (int ni = 0; ni < 4; ni++) acc[mi][ni] = f32x4{0.f, 0.f, 0.f, 0.f};

  gload16(aSrc, &lsA[0][aDst]);
#pragma unroll
  for (int i2 = 0; i2 < 2; i2++) gload16(bSrc[i2], &lsB[0][bDst[i2]]);

  auto compute = [&](const u16* pa, const u16* pb) {
    short8 af[2], bf[4];
#pragma unroll
    for (int mi = 0; mi < 2; mi++) af[mi] = *(const short8*)(pa + aOff[mi]);
#pragma unroll
    for (int ni = 0; ni < 4; ni++) bf[ni] = *(const short8*)(pb + bOff[ni]);
#pragma unroll
    for (int mi = 0; mi < 2; mi++)
#pragma unroll
      for (int ni = 0; ni < 4; ni++)
        acc[mi][ni] = MFMA_BF16(af[mi], bf[ni], acc[mi][ni]);
  };

  for (int kt = 0; kt < 31; kt++) {
    int cur = kt & 1;
    __syncthreads();
    gload16(aSrc + (kt + 1) * 32, &lsA[cur ^ 1][aDst]);
#pragma unroll
    for (int i2 = 0; i2 < 2; i2++)
      gload16(bSrc[i2] + (kt + 1) * 32, &lsB[cur ^ 1][bDst[i2]]);
    compute(lsA[cur], lsB[cur]);
  }
  __syncthreads();
  compute(lsA[1], lsB[1]);

#pragma unroll
  for (int mi = 0; mi < 2; mi++)
#pragma unroll
    for (int j = 0; j < 4; j++) {
      int grow = m0 + mi * 16 + c * 4 + j;
#pragma unroll
      for (int ni = 0; ni < 4; ni++) {
        int gcol = n0 + ni * 16 + r;
        out[(size_t)grow * D + gcol] = acc[mi][ni][j] + bias[gcol];
      }
    }
}

extern "C" void kernel_launch(void* const* d_in, const int* in_sizes, int n_in,
                              void* d_out, int out_size, void* d_ws, size_t ws_size,
                              hipStream_t stream) {
  const float* Q = (const float*)d_in[0];
  const float* K = (const float*)d_in[1];
  const float* V = (const float*)d_in[2];
  const float* Wq = (const float*)d_in[3];
  const float* Wk = (const float*)d_in[4];
  const float* Wv = (const float*)d_in[5];
  const float* Wo = (const float*)d_in[6];
  const float* bq = (const float*)d_in[7];
  const float* bk = (const float*)d_in[8];
  const float* bv = (const float*)d_in[9];
  const float* bo = (const float*)d_in[10];
  float* out = (float*)d_out;

  char* ws = (char*)d_ws;
  u16* wT = (u16*)(ws);
  u16* woT = wT + (size_t)3 * 1024 * 1024;
  float* ct = (float*)(ws + 8388608);
  float* st = (float*)(ws + 8650752);
  u16* qbuf = (u16*)(ws + 8912896);
  u16* kbuf = (u16*)(ws + 17301504);
  u16* vbuf = (u16*)(ws + 25690112);
  u16* obuf = (u16*)(ws + 34078720);
  u16* xb = (u16*)(ws + 42467328);

  if (ws_size >= (size_t)67633152) {
    prep_kernel<true><<<dim3(10496), 256, 0, stream>>>(Wq, Wk, Wv, Wo, wT, ct, st,
                                                       Q, K, V, xb);
    proj_gemm_staged<<<dim3(768), 256, 0, stream>>>(xb, wT, bq, bk, bv, ct, st,
                                                    qbuf, kbuf, vbuf);
  } else {
    prep_kernel<false><<<dim3(4352), 256, 0, stream>>>(Wq, Wk, Wv, Wo, wT, ct, st,
                                                       Q, K, V, xb);
    proj_gemm_f32<<<dim3(768), 256, 0, stream>>>(Q, K, V, wT, bq, bk, bv, ct, st,
                                                 qbuf, kbuf, vbuf);
  }
  attn_kernel<<<dim3(512), 256, 0, stream>>>(qbuf, kbuf, vbuf, obuf);
  oproj_gemm_staged<<<dim3(512), 256, 0, stream>>>(obuf, woT, bo, out);
}

// Round 9
// 240.979 us; speedup vs baseline: 1.1186x; 1.0622x over previous
//
#include <hip/hip_runtime.h>

typedef __attribute__((ext_vector_type(8))) short short8;
typedef __attribute__((ext_vector_type(4))) float f32x4;
typedef __attribute__((ext_vector_type(2))) unsigned int u32x2;
typedef unsigned short u16;
typedef unsigned int u32;

#define MFMA_BF16(a, b, c) __builtin_amdgcn_mfma_f32_16x16x32_bf16((a), (b), (c), 0, 0, 0)

constexpr int D = 1024;
constexpr int L = 2048;
constexpr int NHEAD = 16;
constexpr int HD = 64;
// fold softmax scale (1/8) and log2(e) into q at projection time
constexpr float QLAMBDA = 0.125f * 1.44269504088896340736f;

__device__ __forceinline__ u16 f2bf(float f) {
  unsigned u = __builtin_bit_cast(unsigned, f);
  u = (u + 0x7fffu + ((u >> 16) & 1u)) >> 16;
  return (u16)u;
}

// hardware bf16 convert (RNE), 1 VALU inst (no builtin on gfx950 -- inline asm)
__device__ __forceinline__ u16 cvt1(float f) {
  unsigned o;
  asm("v_cvt_pk_bf16_f32 %0, %1, %1" : "=v"(o) : "v"(f));
  return (u16)o;
}

// pack two f32 -> u32 of 2 bf16 (lo = a, hi = b)
__device__ __forceinline__ u32 cvtpk(float a, float b) {
  u32 o;
  asm("v_cvt_pk_bf16_f32 %0, %1, %2" : "=v"(o) : "v"(a), "v"(b));
  return o;
}

__device__ __forceinline__ short8 cvt8(f32x4 lo, f32x4 hi) {
  short8 r;
  r[0] = (short)f2bf(lo[0]); r[1] = (short)f2bf(lo[1]);
  r[2] = (short)f2bf(lo[2]); r[3] = (short)f2bf(lo[3]);
  r[4] = (short)f2bf(hi[0]); r[5] = (short)f2bf(hi[1]);
  r[6] = (short)f2bf(hi[2]); r[7] = (short)f2bf(hi[3]);
  return r;
}

// async global->LDS, 16B per lane. dst must be wave-uniform; per-lane global src.
__device__ __forceinline__ void gload16(const u16* src, u16* dst) {
  __builtin_amdgcn_global_load_lds(
      (const __attribute__((address_space(1))) u32*)(src),
      (__attribute__((address_space(3))) u32*)(dst), 16, 0, 0);
}

// ---------- merged prep: weight transpose | RoPE tables | X f32->bf16 ----------
template <bool DO_CVT>
__global__ __launch_bounds__(256) void prep_kernel(
    const float* W0, const float* W1, const float* W2, const float* W3, u16* wTout,
    float* ct, float* st,
    const float* Q, const float* K, const float* V, u16* xb) {
  int i = blockIdx.x;
  if (i < 4096) {
    int z = i >> 10, bx = i & 31, by = (i >> 5) & 31;
    const float* W = z == 0 ? W0 : z == 1 ? W1 : z == 2 ? W2 : W3;
    u16* o = wTout + (size_t)z * D * D;
    __shared__ float t[32][33];
    int x = threadIdx.x & 31, y = threadIdx.x >> 5;
    int k0 = bx * 32, n0 = by * 32;
#pragma unroll
    for (int q = 0; q < 4; q++) {
      int ky = y * 4 + q;
      t[ky][x] = W[(size_t)(k0 + ky) * D + n0 + x];
    }
    __syncthreads();
#pragma unroll
    for (int q = 0; q < 4; q++) {
      int ny = y * 4 + q;
      o[(size_t)(n0 + ny) * D + k0 + x] = f2bf(t[x][ny]);
    }
  } else if (i < 4352) {
    int t = (i - 4096) * 256 + threadIdx.x;  // L*32 = 65536
    int ii = t & 31, pos = t >> 5;
    float invf = powf(10000.0f, -(float)ii / 32.0f);
    float ang = (float)pos * invf;
    ct[t] = cosf(ang);
    st[t] = sinf(ang);
  } else if constexpr (DO_CVT) {
    int j = i - 4352;
    int zz = j / 2048, bx = j - zz * 2048;
    const float* src = zz == 0 ? Q : zz == 1 ? K : V;
    u16* dst = xb + (size_t)zz * 4096 * D;
    int t = bx * 256 + threadIdx.x;
    const float* p = src + (size_t)t * 8;
    f32x4 lo = *(const f32x4*)p;
    f32x4 hi = *(const f32x4*)(p + 4);
    *(short8*)(dst + (size_t)t * 8) = cvt8(lo, hi);
  }
}

// ======== staged GEMM core (128x128 tile, BK=32, LDS dbuf, gload_lds) ========

// ---------- fused QKV projection GEMM + bias + RoPE epilogue ----------
// Epilogue uses coalesced wide stores: q/k bounce through XOR-swizzled per-wave
// LDS scratch then 16B stores; vT packs 4 consecutive ll per lane into 8B stores.
__global__ __launch_bounds__(256, 3) void proj_gemm_staged(
    const u16* xb, const u16* wT,
    const float* bq, const float* bk, const float* bv,
    const float* ct, const float* st,
    u16* qo, u16* ko, u16* vT) {
  int i = blockIdx.x;  // 768 blocks, bijective XCD swizzle (768%8==0)
  int swz = (i & 7) * 96 + (i >> 3);
  int z = swz >> 8;
  int bx = swz & 7;
  int by = (swz >> 3) & 31;

  const u16* A = xb + (size_t)z * 4096 * D;
  const u16* W = wT + (size_t)z * D * D;
  const float* bias = z == 0 ? bq : z == 1 ? bk : bv;

  int w = threadIdx.x >> 6, lane = threadIdx.x & 63;
  int r = lane & 15, c = lane >> 4;
  int wr = w >> 1, wc = w & 1;
  int m0 = by * 128 + wr * 64;
  int n0 = bx * 128 + wc * 64;

  __shared__ __align__(16) u16 lsA[2][4096];
  __shared__ __align__(16) u16 lsB[2][4096];
  __shared__ __align__(16) u16 eps[4][16][64];  // per-wave epilogue scratch

  const u16* aSrc[2];
  const u16* bSrc[2];
  int dstOff[2];
#pragma unroll
  for (int i2 = 0; i2 < 2; i2++) {
    int q0 = i2 * 256 + w * 64;
    int qq = q0 + lane;
    int t = qq >> 2;
    int gch = (qq & 3) ^ ((t >> 1) & 3);
    aSrc[i2] = A + (size_t)(by * 128 + t) * D + gch * 8;
    bSrc[i2] = W + (size_t)(bx * 128 + t) * D + gch * 8;
    dstOff[i2] = q0 * 8;
  }

  int aOff[4], bOff[4];
#pragma unroll
  for (int mi = 0; mi < 4; mi++) {
    int rowA = wr * 64 + mi * 16 + r;
    aOff[mi] = rowA * 32 + ((c ^ ((rowA >> 1) & 3)) << 3);
    int rowB = wc * 64 + mi * 16 + r;
    bOff[mi] = rowB * 32 + ((c ^ ((rowB >> 1) & 3)) << 3);
  }

  f32x4 acc[4][4];
#pragma unroll
  for (int mi = 0; mi < 4; mi++)
#pragma unroll
    for (int ni = 0; ni < 4; ni++) acc[mi][ni] = f32x4{0.f, 0.f, 0.f, 0.f};

#pragma unroll
  for (int i2 = 0; i2 < 2; i2++) {
    gload16(aSrc[i2], &lsA[0][dstOff[i2]]);
    gload16(bSrc[i2], &lsB[0][dstOff[i2]]);
  }

  auto compute = [&](const u16* pa, const u16* pb) {
    short8 af[4], bf[4];
#pragma unroll
    for (int mi = 0; mi < 4; mi++) af[mi] = *(const short8*)(pa + aOff[mi]);
#pragma unroll
    for (int ni = 0; ni < 4; ni++) bf[ni] = *(const short8*)(pb + bOff[ni]);
#pragma unroll
    for (int mi = 0; mi < 4; mi++)
#pragma unroll
      for (int ni = 0; ni < 4; ni++)
        acc[mi][ni] = MFMA_BF16(af[mi], bf[ni], acc[mi][ni]);
  };

  for (int kt = 0; kt < 31; kt++) {
    int cur = kt & 1;
    __syncthreads();
#pragma unroll
    for (int i2 = 0; i2 < 2; i2++) {
      gload16(aSrc[i2] + (kt + 1) * 32, &lsA[cur ^ 1][dstOff[i2]]);
      gload16(bSrc[i2] + (kt + 1) * 32, &lsB[cur ^ 1][dstOff[i2]]);
    }
    compute(lsA[cur], lsB[cur]);
  }
  __syncthreads();
  compute(lsA[1], lsB[1]);

  int h = n0 >> 6;
  int b = m0 >> 11;  // uniform per block (128-row tile never crosses batch)
  if (z < 2) {
    u16* o = (z == 0) ? qo : ko;
    float lam = (z == 0) ? QLAMBDA : 1.0f;
#pragma unroll
    for (int mi = 0; mi < 4; mi++) {
      // write phase: RoPE into swizzled per-wave scratch (attn-plds pattern, 0 conflicts)
#pragma unroll
      for (int j = 0; j < 4; j++) {
        int prow = c * 4 + j;
        int ll = (m0 + mi * 16 + prow) & 2047;
        int xr = (prow & 7) << 3;
#pragma unroll
        for (int ni = 0; ni < 2; ni++) {
          int d = ni * 16 + r;
          float x1 = acc[mi][ni][j] + bias[n0 + d];
          float x2 = acc[mi][ni + 2][j] + bias[n0 + 32 + d];
          float cs = ct[ll * 32 + d], sn = st[ll * 32 + d];
          eps[w][prow][d ^ xr]        = cvt1((x1 * cs - x2 * sn) * lam);
          eps[w][prow][(d + 32) ^ xr] = cvt1((x2 * cs + x1 * sn) * lam);
        }
      }
      // read phase: 16B coalesced stores (full 128B rows)
      int ll2 = (m0 + mi * 16 + r) & 2047;
      size_t dst = ((size_t)(b * NHEAD + h) * L + ll2) * HD;
      int xrr = (r & 7) << 3;
      short8 v0 = *(const short8*)&eps[w][r][(c * 8) ^ xrr];
      short8 v1 = *(const short8*)&eps[w][r][(32 + c * 8) ^ xrr];
      *(short8*)(o + dst + c * 8) = v0;
      *(short8*)(o + dst + 32 + c * 8) = v1;
    }
  } else {
#pragma unroll
    for (int ni = 0; ni < 4; ni++) {
      int d = ni * 16 + r;
      float bs = bias[n0 + d];
      size_t vrow = ((size_t)(b * NHEAD + h) * HD + d) * L;
#pragma unroll
      for (int mi = 0; mi < 4; mi++) {
        u32 lo = cvtpk(acc[mi][ni][0] + bs, acc[mi][ni][1] + bs);
        u32 hi = cvtpk(acc[mi][ni][2] + bs, acc[mi][ni][3] + bs);
        int ll = (m0 + mi * 16 + c * 4) & 2047;
        *(u32x2*)(vT + vrow + ll) = u32x2{lo, hi};
      }
    }
  }
}

// ---------- fallback projection (f32 A direct from global), if ws too small ----------
__global__ __launch_bounds__(256) void proj_gemm_f32(
    const float* Qf, const float* Kf, const float* Vf, const u16* wT,
    const float* bq, const float* bk, const float* bv,
    const float* ct, const float* st,
    u16* qo, u16* ko, u16* vT) {
  int i = blockIdx.x;
  int swz = (i & 7) * 96 + (i >> 3);
  int z = swz >> 8;
  int bx = swz & 7;
  int by = (swz >> 3) & 31;

  const u16* W = wT + (size_t)z * D * D;
  const float* bias = z == 0 ? bq : z == 1 ? bk : bv;

  int w = threadIdx.x >> 6, lane = threadIdx.x & 63;
  int r = lane & 15, c = lane >> 4;
  int wr = w >> 1, wc = w & 1;
  int m0 = by * 128 + wr * 64;
  int n0 = bx * 128 + wc * 64;

  const float* Af = z == 0 ? Qf : z == 1 ? Kf : Vf;
  const float* a0f = Af + (size_t)(m0 + r) * D + c * 8;
  const u16* b0 = W + (size_t)(n0 + r) * D + c * 8;

  f32x4 acc[4][4];
#pragma unroll
  for (int mi = 0; mi < 4; mi++)
#pragma unroll
    for (int ni = 0; ni < 4; ni++) acc[mi][ni] = f32x4{0.f, 0.f, 0.f, 0.f};

  for (int kk = 0; kk < D; kk += 32) {
    short8 af[4], bf[4];
#pragma unroll
    for (int mi = 0; mi < 4; mi++) {
      const float* ap = a0f + (size_t)mi * 16 * D;
      af[mi] = cvt8(*(const f32x4*)ap, *(const f32x4*)(ap + 4));
    }
#pragma unroll
    for (int ni = 0; ni < 4; ni++) bf[ni] = *(const short8*)(b0 + (size_t)ni * 16 * D);
#pragma unroll
    for (int mi = 0; mi < 4; mi++)
#pragma unroll
      for (int ni = 0; ni < 4; ni++)
        acc[mi][ni] = MFMA_BF16(af[mi], bf[ni], acc[mi][ni]);
    a0f += 32;
    b0 += 32;
  }

  int h = n0 >> 6;
#pragma unroll
  for (int mi = 0; mi < 4; mi++) {
#pragma unroll
    for (int j = 0; j < 4; j++) {
      int grow = m0 + mi * 16 + c * 4 + j;
      int b = grow >> 11, ll = grow & 2047;
      if (z < 2) {
        u16* o = (z == 0) ? qo : ko;
        float lam = (z == 0) ? QLAMBDA : 1.0f;
        size_t dst = ((size_t)(b * NHEAD + h) * L + ll) * HD;
#pragma unroll
        for (int ni = 0; ni < 2; ni++) {
          int d = ni * 16 + r;
          float x1 = acc[mi][ni][j] + bias[n0 + d];
          float x2 = acc[mi][ni + 2][j] + bias[n0 + 32 + d];
          float cs = ct[ll * 32 + d], sn = st[ll * 32 + d];
          o[dst + d]      = cvt1((x1 * cs - x2 * sn) * lam);
          o[dst + d + 32] = cvt1((x2 * cs + x1 * sn) * lam);
        }
      } else {
#pragma unroll
        for (int ni = 0; ni < 4; ni++) {
          int d = ni * 16 + r;
          float val = acc[mi][ni][j] + bias[n0 + d];
          vT[((size_t)(b * NHEAD + h) * HD + d) * L + ll] = cvt1(val);
        }
      }
    }
  }
}

// ---------- causal flash attention, pair-balanced (unchanged from R8) ----------
__global__ __launch_bounds__(256) void attn_kernel(const u16* qg, const u16* kg,
                                                   const u16* vg, u16* O) {
  int i = blockIdx.x;
  int xcd = i & 7, j = i >> 3;        // j in [0,64)
  int bh = xcd * 4 + (j & 3);         // 4 heads per XCD -> K/V L2 affinity
  int a = j >> 2;                     // pair index in [0,16)
  int qtA = a, qtB = 31 - a;          // 64-row tiles; B is the heavy one

  int w = threadIdx.x >> 6, lane = threadIdx.x & 63;
  int r = lane & 15, c = lane >> 4;
  int qbA = qtA * 64 + w * 16;
  int qbB = qtB * 64 + w * 16;

  const u16* qp = qg + (size_t)bh * L * HD;
  const u16* kp = kg + (size_t)bh * L * HD;
  const u16* vp = vg + (size_t)bh * HD * L;

  __shared__ __align__(16) u16 kls[2][4096];
  __shared__ __align__(16) u16 vls[2][4096];
  __shared__ __align__(16) u16 plds[4][16][64];

  short8 aqA0 = *(const short8*)(qp + (size_t)(qbA + r) * HD + c * 8);
  short8 aqA1 = *(const short8*)(qp + (size_t)(qbA + r) * HD + 32 + c * 8);
  short8 aqB0 = *(const short8*)(qp + (size_t)(qbB + r) * HD + c * 8);
  short8 aqB1 = *(const short8*)(qp + (size_t)(qbB + r) * HD + 32 + c * 8);

  const short one_bf = (short)0x3F80;
  short8 ones = {one_bf, one_bf, one_bf, one_bf, one_bf, one_bf, one_bf, one_bf};

  f32x4 oA[4], oB[4];
  f32x4 sacA = f32x4{0.f, 0.f, 0.f, 0.f};
  f32x4 sacB = f32x4{0.f, 0.f, 0.f, 0.f};
#pragma unroll
  for (int n = 0; n < 4; n++) {
    oA[n] = f32x4{0.f, 0.f, 0.f, 0.f};
    oB[n] = f32x4{0.f, 0.f, 0.f, 0.f};
  }

  int nkt = qtB + 1;  // = 32 - a >= 17

  // prologue: stage tile 0
#pragma unroll
  for (int rd = 0; rd < 2; rd++) {
    int q0 = (rd * 4 + w) << 6;
    int qq = q0 + lane;
    int row = qq >> 3;
    int gch = (qq & 7) ^ (row & 7);
    gload16(kp + (size_t)row * HD + gch * 8, &kls[0][q0 * 8]);
    gload16(vp + (size_t)row * L + gch * 8, &vls[0][q0 * 8]);
  }

  for (int kt = 0; kt < nkt; kt++) {
    int cur = kt & 1;
    __syncthreads();  // drains vmcnt: stage of buf[cur] complete
    if (kt + 1 < nkt) {
      int kb2 = (kt + 1) * 64;
      const u16* kp2 = kp + (size_t)kb2 * HD;
      const u16* vp2 = vp + kb2;
#pragma unroll
      for (int rd = 0; rd < 2; rd++) {
        int q0 = (rd * 4 + w) << 6;
        int qq = q0 + lane;
        int row = qq >> 3;
        int gch = (qq & 7) ^ (row & 7);
        gload16(kp2 + (size_t)row * HD + gch * 8, &kls[cur ^ 1][q0 * 8]);
        gload16(vp2 + (size_t)row * L + gch * 8, &vls[cur ^ 1][q0 * 8]);
      }
    }
    const u16* kb_ = kls[cur];
    const u16* vb_ = vls[cur];
    int kbase = kt * 64;

    auto do_tile = [&](const short8& qf0, const short8& qf1, f32x4* o, f32x4& sac,
                       int qb, bool edge) {
      f32x4 S[4];
#pragma unroll
      for (int ks = 0; ks < 4; ks++) {
        int row = ks * 16 + r;
        short8 kf0 = *(const short8*)(kb_ + row * 64 + ((c ^ (row & 7)) << 3));
        short8 kf1 = *(const short8*)(kb_ + row * 64 + (((4 + c) ^ (row & 7)) << 3));
        S[ks] = f32x4{0.f, 0.f, 0.f, 0.f};
        S[ks] = MFMA_BF16(qf0, kf0, S[ks]);
        S[ks] = MFMA_BF16(qf1, kf1, S[ks]);
      }
#pragma unroll
      for (int j4 = 0; j4 < 4; j4++) {
        float p0 = exp2f(S[0][j4]);
        float p1 = exp2f(S[1][j4]);
        float p2 = exp2f(S[2][j4]);
        float p3 = exp2f(S[3][j4]);
        if (edge) {
          int qrow = qb + c * 4 + j4;
          if (kbase + r > qrow) p0 = 0.f;
          if (kbase + 16 + r > qrow) p1 = 0.f;
          if (kbase + 32 + r > qrow) p2 = 0.f;
          if (kbase + 48 + r > qrow) p3 = 0.f;
        }
        int prow = c * 4 + j4, xr = (prow & 7) << 3;
        plds[w][prow][(r) ^ xr]      = cvt1(p0);
        plds[w][prow][(16 + r) ^ xr] = cvt1(p1);
        plds[w][prow][(32 + r) ^ xr] = cvt1(p2);
        plds[w][prow][(48 + r) ^ xr] = cvt1(p3);
      }
      int xrr = (r & 7) << 3;
      short8 pa0 = *(const short8*)&plds[w][r][(c * 8) ^ xrr];
      short8 pa1 = *(const short8*)&plds[w][r][(32 + c * 8) ^ xrr];
      sac = MFMA_BF16(pa0, ones, sac);
      sac = MFMA_BF16(pa1, ones, sac);
#pragma unroll
      for (int n = 0; n < 4; n++) {
        int row = n * 16 + r;
        short8 vf0 = *(const short8*)(vb_ + row * 64 + ((c ^ (row & 7)) << 3));
        short8 vf1 = *(const short8*)(vb_ + row * 64 + (((4 + c) ^ (row & 7)) << 3));
        o[n] = MFMA_BF16(pa0, vf0, o[n]);
        o[n] = MFMA_BF16(pa1, vf1, o[n]);
      }
    };

    // heavy tile B: active every iteration; edge only on the last
    do_tile(aqB0, aqB1, oB, sacB, qbB, kt == nkt - 1);
    // light tile A: active while kt <= a; edge at kt == a
    if (kt <= qtA) do_tile(aqA0, aqA1, oA, sacA, qbA, kt == qtA);
  }

  int b = bh >> 4, h = bh & 15;
#pragma unroll
  for (int j4 = 0; j4 < 4; j4++) {
    int qrowA = qbA + c * 4 + j4;
    int qrowB = qbB + c * 4 + j4;
    float invA = 1.0f / sacA[j4];
    float invB = 1.0f / sacB[j4];
#pragma unroll
    for (int n = 0; n < 4; n++) {
      O[((size_t)(b * L + qrowA)) * D + h * HD + n * 16 + r] = cvt1(oA[n][j4] * invA);
      O[((size_t)(b * L + qrowB)) * D + h * HD + n * 16 + r] = cvt1(oB[n][j4] * invB);
    }
  }
}

// ---------- output projection (64x128 tile, 512 blocks = 2/CU), f32 out + bias ----------
__global__ __launch_bounds__(256) void oproj_gemm_staged(const u16* Ag, const u16* wT,
                                                         const float* bias, float* out) {
  int i = blockIdx.x;  // 512 blocks, bijective XCD swizzle (512%8==0)
  int swz = (i & 7) * 64 + (i >> 3);
  int bx = swz & 7, by = swz >> 3;  // bx: N tile (128), by: M tile (64)

  int w = threadIdx.x >> 6, lane = threadIdx.x & 63;
  int r = lane & 15, c = lane >> 4;
  int wr = w >> 1, wc = w & 1;
  int m0 = by * 64 + wr * 32;
  int n0 = bx * 128 + wc * 64;

  __shared__ __align__(16) u16 lsA[2][2048];  // 64 rows x 32 k
  __shared__ __align__(16) u16 lsB[2][4096];  // 128 rows x 32 k

  // A staging: 1 gload/thread (64x32 = 4KB/buffer)
  int qqA = w * 64 + lane;
  int tA = qqA >> 2;
  int gchA = (qqA & 3) ^ ((tA >> 1) & 3);
  const u16* aSrc = Ag + (size_t)(by * 64 + tA) * D + gchA * 8;
  int aDst = (w * 64) * 8;

  // B staging: 2 gloads/thread (128x32 = 8KB/buffer)
  const u16* bSrc[2];
  int bDst[2];
#pragma unroll
  for (int i2 = 0; i2 < 2; i2++) {
    int q0 = i2 * 256 + w * 64;
    int qq = q0 + lane;
    int t = qq >> 2;
    int gch = (qq & 3) ^ ((t >> 1) & 3);
    bSrc[i2] = wT + (size_t)(bx * 128 + t) * D + gch * 8;
    bDst[i2] = q0 * 8;
  }

  int aOff[2], bOff[4];
#pragma unroll
  for (int mi = 0; mi < 2; mi++) {
    int rowA = wr * 32 + mi * 16 + r;
    aOff[mi] = rowA * 32 + ((c ^ ((rowA >> 1) & 3)) << 3);
  }
#pragma unroll
  for (int ni = 0; ni < 4; ni++) {
    int rowB = wc * 64 + ni * 16 + r;
    bOff[ni] = rowB * 32 + ((c ^ ((rowB >> 1) & 3)) << 3);
  }

  f32x4 acc[2][4];
#pragma unroll
  for (int mi = 0; mi < 2; mi++)
#pragma unroll
    for (int ni = 0; ni < 4; ni++) acc[mi][ni] = f32x4{0.f, 0.f, 0.f, 0.f};

  gload16(aSrc, &lsA[0][aDst]);
#pragma unroll
  for (int i2 = 0; i2 < 2; i2++) gload16(bSrc[i2], &lsB[0][bDst[i2]]);

  auto compute = [&](const u16* pa, const u16* pb) {
    short8 af[2], bf[4];
#pragma unroll
    for (int mi = 0; mi < 2; mi++) af[mi] = *(const short8*)(pa + aOff[mi]);
#pragma unroll
    for (int ni = 0; ni < 4; ni++) bf[ni] = *(const short8*)(pb + bOff[ni]);
#pragma unroll
    for (int mi = 0; mi < 2; mi++)
#pragma unroll
      for (int ni = 0; ni < 4; ni++)
        acc[mi][ni] = MFMA_BF16(af[mi], bf[ni], acc[mi][ni]);
  };

  for (int kt = 0; kt < 31; kt++) {
    int cur = kt & 1;
    __syncthreads();
    gload16(aSrc + (kt + 1) * 32, &lsA[cur ^ 1][aDst]);
#pragma unroll
    for (int i2 = 0; i2 < 2; i2++)
      gload16(bSrc[i2] + (kt + 1) * 32, &lsB[cur ^ 1][bDst[i2]]);
    compute(lsA[cur], lsB[cur]);
  }
  __syncthreads();
  compute(lsA[1], lsB[1]);

#pragma unroll
  for (int mi = 0; mi < 2; mi++)
#pragma unroll
    for (int j = 0; j < 4; j++) {
      int grow = m0 + mi * 16 + c * 4 + j;
#pragma unroll
      for (int ni = 0; ni < 4; ni++) {
        int gcol = n0 + ni * 16 + r;
        out[(size_t)grow * D + gcol] = acc[mi][ni][j] + bias[gcol];
      }
    }
}

extern "C" void kernel_launch(void* const* d_in, const int* in_sizes, int n_in,
                              void* d_out, int out_size, void* d_ws, size_t ws_size,
                              hipStream_t stream) {
  const float* Q = (const float*)d_in[0];
  const float* K = (const float*)d_in[1];
  const float* V = (const float*)d_in[2];
  const float* Wq = (const float*)d_in[3];
  const float* Wk = (const float*)d_in[4];
  const float* Wv = (const float*)d_in[5];
  const float* Wo = (const float*)d_in[6];
  const float* bq = (const float*)d_in[7];
  const float* bk = (const float*)d_in[8];
  const float* bv = (const float*)d_in[9];
  const float* bo = (const float*)d_in[10];
  float* out = (float*)d_out;

  char* ws = (char*)d_ws;
  u16* wT = (u16*)(ws);
  u16* woT = wT + (size_t)3 * 1024 * 1024;
  float* ct = (float*)(ws + 8388608);
  float* st = (float*)(ws + 8650752);
  u16* qbuf = (u16*)(ws + 8912896);
  u16* kbuf = (u16*)(ws + 17301504);
  u16* vbuf = (u16*)(ws + 25690112);
  u16* obuf = (u16*)(ws + 34078720);
  u16* xb = (u16*)(ws + 42467328);

  if (ws_size >= (size_t)67633152) {
    prep_kernel<true><<<dim3(10496), 256, 0, stream>>>(Wq, Wk, Wv, Wo, wT, ct, st,
                                                       Q, K, V, xb);
    proj_gemm_staged<<<dim3(768), 256, 0, stream>>>(xb, wT, bq, bk, bv, ct, st,
                                                    qbuf, kbuf, vbuf);
  } else {
    prep_kernel<false><<<dim3(4352), 256, 0, stream>>>(Wq, Wk, Wv, Wo, wT, ct, st,
                                                       Q, K, V, xb);
    proj_gemm_f32<<<dim3(768), 256, 0, stream>>>(Q, K, V, wT, bq, bk, bv, ct, st,
                                                 qbuf, kbuf, vbuf);
  }
  attn_kernel<<<dim3(512), 256, 0, stream>>>(qbuf, kbuf, vbuf, obuf);
  oproj_gemm_staged<<<dim3(512), 256, 0, stream>>>(obuf, woT, bo, out);
}